// Round 6
// baseline (189.193 us; speedup 1.0000x reference)
//
#include <hip/hip_runtime.h>

#define B_    1024
#define TI_   2
#define TE_   3
#define AB_   (TI_ * TE_)
#define BIN_  16
#define BOUT_ 32

typedef float f4 __attribute__((ext_vector_type(4)));

#define XGET(q, L) (((L) & 3) == 0 ? q[(L) >> 2].x : \
                    ((L) & 3) == 1 ? q[(L) >> 2].y : \
                    ((L) & 3) == 2 ? q[(L) >> 2].z : q[(L) >> 2].w)

// out[slice, o, l, k] = sum_i X[slice, i, l] * W[ab, i, o, k]
//
// One thread per (slice-in-block, o, k-QUAD): acc[NSH] float4 (4 k each) ->
// 3.4x fewer threads re-reading the X row from LDS than k-scalar mapping
// (LDS read volume was the R5 wall). W: 16x4 scalar dwords hoisted per slice
// (L2-resident). X: staged in LDS once, broadcast ds_read_b128 per i.
// Output: packed LDS tile (b32 writes, odd stride -> conflict-light) then
// flat float4 flush (perfectly coalesced, proven R1/R5).
template<int NSH, int SPB, int BLOCK>
__global__ __launch_bounds__(BLOCK)
void conv_q(const float* __restrict__ X, const float* __restrict__ W,
            float* __restrict__ OUT) {
    constexpr int QT   = (NSH + 3) / 4;      // k-quads per o
    constexpr int TS   = BOUT_ * QT;         // threads per slice
    constexpr int LP   = QT * 4;             // padded X row
    constexpr int NOUT = BOUT_ * NSH * NSH;

    __shared__ __attribute__((aligned(16))) float xs[SPB * BIN_ * LP];
    __shared__ __attribute__((aligned(16))) float os[SPB * NOUT];

    const int tid = threadIdx.x;

    // ---- stage X (coalesced; pad slots zeroed) ----
    {
        const float* Xg = X + (size_t)blockIdx.x * (SPB * BIN_ * NSH);
        for (int e = tid; e < SPB * BIN_ * LP; e += BLOCK) {
            int i = e / LP;
            int l = e % LP;
            xs[e] = (l < NSH) ? Xg[i * NSH + l] : 0.0f;
        }
    }
    __syncthreads();

    if (tid < SPB * TS) {
        const int sl  = tid / TS;
        const int wid = tid - sl * TS;
        const int o   = wid / QT;
        const int q   = wid - o * QT;
        const int k0  = q * 4;
        const int slice = blockIdx.x * SPB + sl;
        const int ab    = slice % AB_;

        // ---- hoist W (this thread's 4 k, all i); clamped tail ----
        const float* Wp = W + (size_t)ab * (BIN_ * BOUT_ * NSH) + o * NSH;
        f4 wreg[BIN_];
#pragma unroll
        for (int i = 0; i < BIN_; ++i) {
#pragma unroll
            for (int kk = 0; kk < 4; ++kk) {
                int k = k0 + kk;
                if (k > NSH - 1) k = NSH - 1;   // valid addr, never stored
                wreg[i][kk] = Wp[i * (BOUT_ * NSH) + k];
            }
        }

        f4 acc[NSH];
#pragma unroll
        for (int l = 0; l < NSH; ++l) acc[l] = (f4){0.f, 0.f, 0.f, 0.f};

        const float* xrow = xs + sl * (BIN_ * LP);
#pragma unroll
        for (int i = 0; i < BIN_; ++i) {
            f4 xq[QT];
#pragma unroll
            for (int c = 0; c < QT; ++c)
                xq[c] = *(const f4*)(xrow + i * LP + 4 * c);   // broadcast b128
#pragma unroll
            for (int l = 0; l < NSH; ++l) {
                const float xv = XGET(xq, l);
                const f4 xb = {xv, xv, xv, xv};
                acc[l] = __builtin_elementwise_fma(xb, wreg[i], acc[l]);  // 2x v_pk_fma_f32
            }
        }

        // ---- stage tile in LDS (packed [o][l][k]); mask tail quad ----
        float* op = os + sl * NOUT + o * (NSH * NSH) + k0;
        if (k0 + 4 <= NSH) {
#pragma unroll
            for (int l = 0; l < NSH; ++l) {
#pragma unroll
                for (int kk = 0; kk < 4; ++kk) op[l * NSH + kk] = acc[l][kk];
            }
        } else {
#pragma unroll
            for (int l = 0; l < NSH; ++l) {
#pragma unroll
                for (int kk = 0; kk < 4; ++kk)
                    if (k0 + kk < NSH) op[l * NSH + kk] = acc[l][kk];
            }
        }
    }
    __syncthreads();

    // ---- flat float4 flush: SPB consecutive slices = contiguous range ----
    f4* dst = (f4*)(OUT + (size_t)blockIdx.x * (SPB * NOUT));
    const f4* src = (const f4*)os;
    constexpr int NC = SPB * NOUT / 4;
    for (int c = tid; c < NC; c += BLOCK) dst[c] = src[c];
}

// l=0: direct coalesced stores, 64 n per block.
__global__ __launch_bounds__(256)
void conv_l0_kernel(const float* __restrict__ X, const float* __restrict__ W,
                    const float* __restrict__ bias, float* __restrict__ OUT) {
    const int o  = threadIdx.x & 31;
    const int ns = threadIdx.x >> 5;   // 0..7
    const int b  = blockIdx.x;
    const int n0 = (b / AB_) * 64;
    const int ab = b % AB_;
    float wv[BIN_];
#pragma unroll
    for (int i = 0; i < BIN_; ++i) wv[i] = W[(ab * BIN_ + i) * BOUT_ + o];
    const float bv = bias[ab * BOUT_ + o];
#pragma unroll
    for (int s = 0; s < 8; ++s) {
        const int n = n0 + ns + s * 8;
        const float* Xp = X + ((size_t)n * AB_ + ab) * BIN_;
        float acc = bv;
#pragma unroll
        for (int i = 0; i < BIN_; ++i) acc = fmaf(Xp[i], wv[i], acc);
        OUT[((size_t)n * AB_ + ab) * BOUT_ + o] = acc;
    }
}

extern "C" void kernel_launch(void* const* d_in, const int* in_sizes, int n_in,
                              void* d_out, int out_size, void* d_ws, size_t ws_size,
                              hipStream_t stream) {
    const float* x0 = (const float*)d_in[0];
    const float* w0 = (const float*)d_in[1];
    const float* x2 = (const float*)d_in[2];
    const float* w2 = (const float*)d_in[3];
    const float* x4 = (const float*)d_in[4];
    const float* w4 = (const float*)d_in[5];
    const float* x6 = (const float*)d_in[6];
    const float* w6 = (const float*)d_in[7];
    const float* x8 = (const float*)d_in[8];
    const float* w8 = (const float*)d_in[9];
    const float* bias = (const float*)d_in[10];
    float* out = (float*)d_out;

    const size_t per = (size_t)B_ * AB_ * BOUT_;
    size_t off0 = 0;
    size_t off2 = off0 + per * 1;
    size_t off4 = off2 + per * 25;
    size_t off6 = off4 + per * 81;
    size_t off8 = off6 + per * 169;

    const int S = B_ * AB_;  // 6144 slices

    //      NSH SPB BLOCK           grid
    conv_q<17, 1, 160><<<S,     160, 0, stream>>>(x8, w8, out + off8);  // os 37 KB
    conv_q<13, 2, 256><<<S / 2, 256, 0, stream>>>(x6, w6, out + off6);  // os 43 KB
    conv_q< 9, 4, 384><<<S / 4, 384, 0, stream>>>(x4, w4, out + off4);  // os 41 KB
    conv_q< 5, 8, 512><<<S / 8, 512, 0, stream>>>(x2, w2, out + off2);  // os 26 KB
    conv_l0_kernel<<<(B_ / 64) * AB_, 256, 0, stream>>>(x0, w0, bias, out + off0);
}

// Round 7
// 150.464 us; speedup vs baseline: 1.2574x; 1.2574x over previous
//
#include <hip/hip_runtime.h>

#define B_    1024
#define TI_   2
#define TE_   3
#define AB_   (TI_ * TE_)
#define BIN_  16
#define BOUT_ 32

typedef float f2 __attribute__((ext_vector_type(2)));
typedef float f4 __attribute__((ext_vector_type(4)));

#define XGET(q, L) (((L) & 3) == 0 ? q[(L) >> 2].x : \
                    ((L) & 3) == 1 ? q[(L) >> 2].y : \
                    ((L) & 3) == 2 ? q[(L) >> 2].z : q[(L) >> 2].w)

// out[slice, o, l, k] = sum_i X[slice, i, l] * W[ab, i, o, k]
//
// Thread = (slice-in-block, o, k-PAIR). acc[NSH] f2 (pk_fma over 2 k).
// k-pair halves waves/slice vs R5 -> halves LDS b128 broadcast-read issue
// (the measured wall: 1 DS pipe/CU, ~12cy/b128) while VGPR stays ~105
// (no R6 occupancy cliff). Last pair overlaps (k0 = min(2p, NSH-2)):
// duplicate k computed identically by two threads -> benign identical
// LDS writes, zero waste, no masks. W hoisted once (2 scalar loads/i).
// Output: LDS tile -> flat float4 flush (proven R1/R5).
template<int NSH, int SPB, int BLOCK>
__global__ __launch_bounds__(BLOCK)
void conv_p2(const float* __restrict__ X, const float* __restrict__ W,
             float* __restrict__ OUT) {
    constexpr int NP   = (NSH + 1) / 2;        // k-pairs per o (last overlaps)
    constexpr int TS   = BOUT_ * NP;           // threads per slice
    constexpr int LP   = ((NSH + 3) / 4) * 4;  // padded X row
    constexpr int QT   = LP / 4;
    constexpr int NOUT = BOUT_ * NSH * NSH;

    __shared__ __attribute__((aligned(16))) float xs[SPB * BIN_ * LP];
    __shared__ __attribute__((aligned(16))) float os[SPB * NOUT];

    const int tid = threadIdx.x;

    // ---- stage X (coalesced; pad slots zeroed) ----
    {
        const float* Xg = X + (size_t)blockIdx.x * (SPB * BIN_ * NSH);
        for (int e = tid; e < SPB * BIN_ * LP; e += BLOCK) {
            int i = e / LP;
            int l = e % LP;
            xs[e] = (l < NSH) ? Xg[i * NSH + l] : 0.0f;
        }
    }
    __syncthreads();

    {
        const int sl  = tid / TS;
        const int wid = tid - sl * TS;
        const int o   = wid / NP;
        const int p   = wid - o * NP;
        const int k0  = (2 * p > NSH - 2) ? (NSH - 2) : (2 * p);
        const int slice = blockIdx.x * SPB + sl;
        const int ab    = slice % AB_;

        // ---- hoist W (this thread's 2 k, all i) ----
        const float* Wp = W + (size_t)ab * (BIN_ * BOUT_ * NSH) + o * NSH + k0;
        f2 wreg[BIN_];
#pragma unroll
        for (int i = 0; i < BIN_; ++i) {
            wreg[i].x = Wp[i * (BOUT_ * NSH)];
            wreg[i].y = Wp[i * (BOUT_ * NSH) + 1];
        }

        f2 acc[NSH];
#pragma unroll
        for (int l = 0; l < NSH; ++l) acc[l] = (f2){0.f, 0.f};

        const float* xrow = xs + sl * (BIN_ * LP);
#pragma unroll
        for (int i = 0; i < BIN_; ++i) {
            f4 xq[QT];
#pragma unroll
            for (int c = 0; c < QT; ++c)
                xq[c] = *(const f4*)(xrow + i * LP + 4 * c);   // broadcast b128
#pragma unroll
            for (int l = 0; l < NSH; ++l) {
                const float xv = XGET(xq, l);
                const f2 xb = {xv, xv};
                acc[l] = __builtin_elementwise_fma(xb, wreg[i], acc[l]);  // v_pk_fma_f32
            }
        }

        // ---- stage tile in LDS (packed [o][l][k]) ----
        float* op = os + sl * NOUT + o * (NSH * NSH) + k0;
#pragma unroll
        for (int l = 0; l < NSH; ++l) {
            op[l * NSH]     = acc[l].x;
            op[l * NSH + 1] = acc[l].y;
        }
    }
    __syncthreads();

    // ---- flat float4 flush: SPB consecutive slices = contiguous range ----
    f4* dst = (f4*)(OUT + (size_t)blockIdx.x * (SPB * NOUT));
    const f4* src = (const f4*)os;
    constexpr int NC = SPB * NOUT / 4;
    for (int c = tid; c < NC; c += BLOCK) dst[c] = src[c];
}

// l=0: direct coalesced stores, 64 n per block.
__global__ __launch_bounds__(256)
void conv_l0_kernel(const float* __restrict__ X, const float* __restrict__ W,
                    const float* __restrict__ bias, float* __restrict__ OUT) {
    const int o  = threadIdx.x & 31;
    const int ns = threadIdx.x >> 5;   // 0..7
    const int b  = blockIdx.x;
    const int n0 = (b / AB_) * 64;
    const int ab = b % AB_;
    float wv[BIN_];
#pragma unroll
    for (int i = 0; i < BIN_; ++i) wv[i] = W[(ab * BIN_ + i) * BOUT_ + o];
    const float bv = bias[ab * BOUT_ + o];
#pragma unroll
    for (int s = 0; s < 8; ++s) {
        const int n = n0 + ns + s * 8;
        const float* Xp = X + ((size_t)n * AB_ + ab) * BIN_;
        float acc = bv;
#pragma unroll
        for (int i = 0; i < BIN_; ++i) acc = fmaf(Xp[i], wv[i], acc);
        OUT[((size_t)n * AB_ + ab) * BOUT_ + o] = acc;
    }
}

extern "C" void kernel_launch(void* const* d_in, const int* in_sizes, int n_in,
                              void* d_out, int out_size, void* d_ws, size_t ws_size,
                              hipStream_t stream) {
    const float* x0 = (const float*)d_in[0];
    const float* w0 = (const float*)d_in[1];
    const float* x2 = (const float*)d_in[2];
    const float* w2 = (const float*)d_in[3];
    const float* x4 = (const float*)d_in[4];
    const float* w4 = (const float*)d_in[5];
    const float* x6 = (const float*)d_in[6];
    const float* w6 = (const float*)d_in[7];
    const float* x8 = (const float*)d_in[8];
    const float* w8 = (const float*)d_in[9];
    const float* bias = (const float*)d_in[10];
    float* out = (float*)d_out;

    const size_t per = (size_t)B_ * AB_ * BOUT_;
    size_t off0 = 0;
    size_t off2 = off0 + per * 1;
    size_t off4 = off2 + per * 25;
    size_t off6 = off4 + per * 81;
    size_t off8 = off6 + per * 169;

    const int S = B_ * AB_;  // 6144 slices

    //       NSH SPB BLOCK          grid        TS   os KB  blocks/CU
    conv_p2<17, 1, 288><<<S,     288, 0, stream>>>(x8, w8, out + off8);  // 288, 37
    conv_p2<13, 2, 448><<<S / 2, 448, 0, stream>>>(x6, w6, out + off6);  // 224, 43
    conv_p2< 9, 2, 320><<<S / 2, 320, 0, stream>>>(x4, w4, out + off4);  // 160, 21
    conv_p2< 5, 4, 384><<<S / 4, 384, 0, stream>>>(x2, w2, out + off2);  //  96, 13
    conv_l0_kernel<<<(B_ / 64) * AB_, 256, 0, stream>>>(x0, w0, bias, out + off0);
}